// Round 3
// baseline (3106.397 us; speedup 1.0000x reference)
//
#include <hip/hip_runtime.h>
#include <cstdint>
#include <cstddef>

#define BB 32
#define NN 24564
#define CC 81
#define CM1 80
#define KTOP 100
#define MAXDET 100
#define CBINS 56          // coarse bins: ((bits-BASE)>>20), score in (0.01, 1.0)
#define CSHIFT 20
#define BASEBITS 0x3C000000u
#define CAP2 2048
#define CHUNKS 64         // row-chunks per image
#define CHROWS 384        // ceil(NN/CHUNKS)

typedef unsigned long long ull;

// ---------------- pass 1: exact softmax + threshold + coarse LDS histogram ----------------
// grid: BB*CHUNKS blocks of 256; block (b,j) handles rows [j*384, ...) of image b.
// Partial hist written non-atomically: histg[block][c][bin].
__global__ __launch_bounds__(256) void softmax_hist_kernel(const float* __restrict__ conf,
                                                           unsigned int* __restrict__ histg) {
    __shared__ unsigned int h[CM1 * CBINS];   // 17920 B
    int tid = threadIdx.x;
    for (int i = tid; i < CM1 * CBINS; i += 256) h[i] = 0u;
    __syncthreads();

    int b = blockIdx.x / CHUNKS, j = blockIdx.x % CHUNKS;
    int n0 = j * CHROWS;
    int n1 = n0 + CHROWS; if (n1 > NN) n1 = NN;

    for (int n = n0 + tid; n < n1; n += 256) {
        const float* row = conf + ((size_t)b * NN + n) * CC;
        float mx = row[0];
        for (int c = 1; c < CC; ++c) mx = fmaxf(mx, row[c]);
        float s = 0.f;
        for (int c = 0; c < CC; ++c) s = __fadd_rn(s, expf(__fsub_rn(row[c], mx)));
        for (int c = 1; c < CC; ++c) {
            float e = expf(__fsub_rn(row[c], mx));
            float sc = __fdiv_rn(e, s);
            if (sc > 0.01f) {
                unsigned int bits = __float_as_uint(sc);
                unsigned int bin = (bits - BASEBITS) >> CSHIFT;
                if (bin >= CBINS) bin = CBINS - 1;
                atomicAdd(&h[(c - 1) * CBINS + bin], 1u);
            }
        }
    }
    __syncthreads();
    unsigned int* dst = histg + (size_t)blockIdx.x * (CM1 * CBINS);
    for (int i = tid; i < CM1 * CBINS; i += 256) dst[i] = h[i];
}

// ---------------- pass 2: per-(b,c) sum partials, find rank-100 bit cut ----------------
__global__ __launch_bounds__(64) void cut_kernel(const unsigned int* __restrict__ histg,
                                                 unsigned int* __restrict__ cuts) {
    int bc = blockIdx.x;              // b*80 + c
    int b = bc / CM1, c = bc % CM1;
    __shared__ unsigned int sh[CBINS];
    int t = threadIdx.x;
    if (t < CBINS) {
        unsigned int sum = 0;
        for (int jj = 0; jj < CHUNKS; ++jj)
            sum += histg[((size_t)(b * CHUNKS + jj) * CM1 + c) * CBINS + t];
        sh[t] = sum;
    }
    __syncthreads();
    if (t == 0) {
        unsigned int total = 0;
        for (int i = 0; i < CBINS; ++i) total += sh[i];
        int Kt = (int)(total < KTOP ? total : KTOP);
        unsigned int cutv = 0xFFFFFFFFu;
        if (Kt > 0) {
            unsigned int cum = 0; int bb2 = 0;
            for (int i = CBINS - 1; i >= 0; --i) {
                cum += sh[i];
                if (cum >= (unsigned)Kt) { bb2 = i; break; }
            }
            unsigned int cutbin = (cum <= CAP2) ? (unsigned)bb2 : (unsigned)(bb2 + 1);
            cutv = BASEBITS + (cutbin << CSHIFT);
        }
        cuts[bc] = cutv;
    }
}

// ---------------- pass 3: recompute identical softmax, collect candidates >= cut ----------------
__global__ __launch_bounds__(256) void collect_kernel(const float* __restrict__ conf,
                                                      const unsigned int* __restrict__ cuts,
                                                      ull* __restrict__ cand,
                                                      unsigned int* __restrict__ ccnt) {
    __shared__ unsigned int lcut[CM1];
    int tid = threadIdx.x;
    int b = blockIdx.x / CHUNKS, j = blockIdx.x % CHUNKS;
    if (tid < CM1) lcut[tid] = cuts[b * CM1 + tid];
    __syncthreads();

    int n0 = j * CHROWS;
    int n1 = n0 + CHROWS; if (n1 > NN) n1 = NN;

    for (int n = n0 + tid; n < n1; n += 256) {
        const float* row = conf + ((size_t)b * NN + n) * CC;
        float mx = row[0];
        for (int c = 1; c < CC; ++c) mx = fmaxf(mx, row[c]);
        float s = 0.f;
        for (int c = 0; c < CC; ++c) s = __fadd_rn(s, expf(__fsub_rn(row[c], mx)));
        for (int c = 1; c < CC; ++c) {
            float e = expf(__fsub_rn(row[c], mx));
            float sc = __fdiv_rn(e, s);
            if (sc > 0.01f) {
                unsigned int bits = __float_as_uint(sc);
                if (bits >= lcut[c - 1]) {
                    int bc = b * CM1 + (c - 1);
                    unsigned int p = atomicAdd(ccnt + bc, 1u);
                    if (p < CAP2)
                        cand[(size_t)bc * CAP2 + p] =
                            (((ull)(~bits)) << 32) | (unsigned int)n;
                }
            }
        }
    }
}

// ---------------- pass 4: per-(b,c) sort candidates + fused box decode + greedy NMS ----------------
__global__ __launch_bounds__(256) void nms_kernel(const ull* __restrict__ cand,
                                                  const unsigned int* __restrict__ ccnt,
                                                  const float* __restrict__ loc,
                                                  const float* __restrict__ priors,
                                                  float* __restrict__ nms_scores,
                                                  float* __restrict__ nms_boxes) {
    int bc = blockIdx.x;
    int bimg = bc / CM1;
    __shared__ ull arr[CAP2];                 // 16 KB
    __shared__ float bx[KTOP][4];
    __shared__ float sv[KTOP];
    __shared__ ull mlo[KTOP], mhi[KTOP];
    __shared__ ull keeplo, keephi;

    int tid = threadIdx.x;
    int cc = (int)ccnt[bc]; if (cc > CAP2) cc = CAP2;
    int S = 1; while (S < cc) S <<= 1; if (S < 2) S = 2;
    const ull* crow = cand + (size_t)bc * CAP2;
    for (int i = tid; i < S; i += 256) arr[i] = (i < cc) ? crow[i] : ~0ull;
    __syncthreads();

    for (int k = 2; k <= S; k <<= 1) {
        for (int jj = k >> 1; jj > 0; jj >>= 1) {
            for (int i = tid; i < S; i += 256) {
                int ixj = i ^ jj;
                if (ixj > i) {
                    ull a = arr[i], b2 = arr[ixj];
                    bool up = ((i & k) == 0);
                    if ((a > b2) == up) { arr[i] = b2; arr[ixj] = a; }
                }
            }
            __syncthreads();
        }
    }

    if (tid < KTOP) {
        float val = 0.f; unsigned int n = 0;
        if (tid < cc) {
            ull kk = arr[tid];
            val = __uint_as_float(~(unsigned int)(kk >> 32));
            n = (unsigned int)(kk & 0xFFFFFFFFu);
        }
        sv[tid] = val;
        // fused decode (bit-identical op order to validated decode_kernel)
        float4 l = reinterpret_cast<const float4*>(loc)[(size_t)bimg * NN + n];
        float4 p = reinterpret_cast<const float4*>(priors)[n];
        float cx = __fadd_rn(__fmul_rn(__fmul_rn(l.x, 0.1f), p.z), p.x);
        float cy = __fadd_rn(__fmul_rn(__fmul_rn(l.y, 0.1f), p.w), p.y);
        float w  = __fmul_rn(expf(__fmul_rn(l.z, 0.2f)), p.z);
        float h  = __fmul_rn(expf(__fmul_rn(l.w, 0.2f)), p.w);
        bx[tid][0] = __fsub_rn(cx, __fmul_rn(w, 0.5f));
        bx[tid][1] = __fsub_rn(cy, __fmul_rn(h, 0.5f));
        bx[tid][2] = __fadd_rn(cx, __fmul_rn(w, 0.5f));
        bx[tid][3] = __fadd_rn(cy, __fmul_rn(h, 0.5f));
    }
    __syncthreads();

    if (tid < KTOP) {
        float x1 = bx[tid][0], y1 = bx[tid][1], x2 = bx[tid][2], y2 = bx[tid][3];
        float ai = __fmul_rn(fmaxf(__fsub_rn(x2, x1), 0.f), fmaxf(__fsub_rn(y2, y1), 0.f));
        ull lo = 0, hi = 0;
        for (int jj = 0; jj < KTOP; ++jj) {
            float jx1 = bx[jj][0], jy1 = bx[jj][1], jx2 = bx[jj][2], jy2 = bx[jj][3];
            float iw = fmaxf(__fsub_rn(fminf(x2, jx2), fmaxf(x1, jx1)), 0.f);
            float ih = fmaxf(__fsub_rn(fminf(y2, jy2), fmaxf(y1, jy1)), 0.f);
            float inter = __fmul_rn(iw, ih);
            float aj = __fmul_rn(fmaxf(__fsub_rn(jx2, jx1), 0.f), fmaxf(__fsub_rn(jy2, jy1), 0.f));
            float denom = __fadd_rn(__fsub_rn(__fadd_rn(ai, aj), inter), 1e-8f);
            float iou = __fdiv_rn(inter, denom);
            if (iou > 0.45f) { if (jj < 64) lo |= (1ull << jj); else hi |= (1ull << (jj - 64)); }
        }
        mlo[tid] = lo; mhi[tid] = hi;
    }
    __syncthreads();

    if (tid == 0) {
        ull klo = 0, khi = 0;
        for (int i = 0; i < KTOP; ++i) {
            ull sup = (mlo[i] & klo) | (mhi[i] & khi);
            bool kp = (sv[i] > 0.f) && (sup == 0ull);
            if (kp) { if (i < 64) klo |= (1ull << i); else khi |= (1ull << (i - 64)); }
        }
        keeplo = klo; keephi = khi;
    }
    __syncthreads();

    if (tid < KTOP) {
        bool kp = (tid < 64) ? ((keeplo >> tid) & 1ull) : ((keephi >> (tid - 64)) & 1ull);
        size_t obase = (size_t)bc * KTOP + tid;
        nms_scores[obase] = kp ? sv[tid] : 0.f;
        float4 o; o.x = bx[tid][0]; o.y = bx[tid][1]; o.z = bx[tid][2]; o.w = bx[tid][3];
        reinterpret_cast<float4*>(nms_boxes)[obase] = o;
    }
}

// ---------------- per-image final top-100 over 8000 candidates ----------------
__global__ __launch_bounds__(256) void final_topk_kernel(const float* __restrict__ nms_scores,
                                                         const float* __restrict__ nms_boxes,
                                                         float* __restrict__ out) {
    int b = blockIdx.x;
    __shared__ ull arr[8192];   // 64 KB
    int tid = threadIdx.x;
    const int NCAND = CM1 * KTOP;              // 8000
    const float* srow = nms_scores + (size_t)b * NCAND;
    for (int i = tid; i < 8192; i += 256) {
        ull key;
        if (i < NCAND) {
            float s = srow[i];
            unsigned int bits = (s > 0.f) ? __float_as_uint(s) : 0u;
            key = (((ull)(~bits)) << 32) | (unsigned int)i;
        } else key = ~0ull;
        arr[i] = key;
    }
    __syncthreads();
    for (int k = 2; k <= 8192; k <<= 1) {
        for (int jj = k >> 1; jj > 0; jj >>= 1) {
            for (int i = tid; i < 8192; i += 256) {
                int ixj = i ^ jj;
                if (ixj > i) {
                    ull a = arr[i], b2 = arr[ixj];
                    bool up = ((i & k) == 0);
                    if ((a > b2) == up) { arr[i] = b2; arr[ixj] = a; }
                }
            }
            __syncthreads();
        }
    }
    if (tid < MAXDET) {
        ull kk = arr[tid];
        unsigned int hb = (unsigned int)(kk >> 32);
        unsigned int idx = (unsigned int)(kk & 0xFFFFFFFFu);
        float val = __uint_as_float(~hb);
        float4 b4 = reinterpret_cast<const float4*>(nms_boxes)[(size_t)b * NCAND + idx];
        reinterpret_cast<float4*>(out)[(size_t)b * MAXDET + tid] = b4;
        out[BB * MAXDET * 4 + b * MAXDET + tid] = val;
        out[BB * MAXDET * 5 + b * MAXDET + tid] = (float)(idx / KTOP + 1);
    }
}

extern "C" void kernel_launch(void* const* d_in, const int* in_sizes, int n_in,
                              void* d_out, int out_size, void* d_ws, size_t ws_size,
                              hipStream_t stream) {
    const float* loc    = (const float*)d_in[0];
    const float* conf   = (const float*)d_in[1];
    const float* priors = (const float*)d_in[2];
    float* out = (float*)d_out;

    // workspace layout (16B-aligned chunks)
    char* ws = (char*)d_ws;
    float* nms_scores = (float*)ws;                                        // 32*8000           = 1.02 MB
    float* nms_boxes  = nms_scores + (size_t)BB * CM1 * KTOP;              // 32*8000*4         = 4.1 MB
    ull*   cand       = (ull*)(nms_boxes + (size_t)BB * CM1 * KTOP * 4);   // 2560*2048*8       = 41.9 MB
    unsigned int* histg = (unsigned int*)(cand + (size_t)BB * CM1 * CAP2); // 2048*80*56*4      = 36.7 MB
    unsigned int* cuts  = histg + (size_t)BB * CHUNKS * CM1 * CBINS;       // 2560
    unsigned int* ccnt  = cuts + (size_t)BB * CM1;                         // 2560

    hipMemsetAsync(ccnt, 0, (size_t)BB * CM1 * sizeof(unsigned int), stream);

    softmax_hist_kernel<<<BB * CHUNKS, 256, 0, stream>>>(conf, histg);
    cut_kernel<<<BB * CM1, 64, 0, stream>>>(histg, cuts);
    collect_kernel<<<BB * CHUNKS, 256, 0, stream>>>(conf, cuts, cand, ccnt);
    nms_kernel<<<BB * CM1, 256, 0, stream>>>(cand, ccnt, loc, priors, nms_scores, nms_boxes);
    final_topk_kernel<<<BB, 256, 0, stream>>>(nms_scores, nms_boxes, out);
}

// Round 4
// 885.710 us; speedup vs baseline: 3.5072x; 3.5072x over previous
//
#include <hip/hip_runtime.h>
#include <cstdint>
#include <cstddef>

#define BB 32
#define NN 24564
#define CC 81
#define CM1 80
#define KTOP 100
#define MAXDET 100
#define CBINS 28          // quarter-octave bins over score in (0.01, 1]
#define CSHIFT 21
#define BASEBITS 0x3C000000u
#define CAP2 2048
#define TILE 128
#define NTILES ((NN + TILE - 1) / TILE)   // 192
#define HWORDS (CM1 * (CBINS / 2))        // 80*14 = 1120 packed u32 words

typedef unsigned long long ull;

// ---------------- pass 1: coalesced tile stage + exact softmax + packed LDS hist ----------------
// grid: BB*NTILES blocks of 256. Partial hist flushed non-atomically per block.
__global__ __launch_bounds__(256) void softmax_hist_kernel(const float* __restrict__ conf,
                                                           unsigned int* __restrict__ histg) {
    __shared__ __align__(16) float tile[TILE * CC];   // 41472 B
    __shared__ unsigned int h[HWORDS];                // 4480 B (u16-packed bin pairs)
    int tid = threadIdx.x;
    for (int i = tid; i < HWORDS; i += 256) h[i] = 0u;

    int b = blockIdx.x / NTILES, j = blockIdx.x % NTILES;
    int n0 = j * TILE;
    int cnt = NN - n0; if (cnt > TILE) cnt = TILE;

    // coalesced float4 stage (cnt*CC always divisible by 4)
    const float4* src4 = reinterpret_cast<const float4*>(conf + ((size_t)b * NN + n0) * CC);
    float4* tile4 = reinterpret_cast<float4*>(tile);
    int tot4 = (cnt * CC) >> 2;
    for (int i = tid; i < tot4; i += 256) tile4[i] = src4[i];
    __syncthreads();

    if (tid < cnt) {
        const float* row = tile + tid * CC;
        float mx = row[0];
        for (int c = 1; c < CC; ++c) mx = fmaxf(mx, row[c]);
        float s = 0.f;
        for (int c = 0; c < CC; ++c) s = __fadd_rn(s, expf(__fsub_rn(row[c], mx)));
        for (int c = 1; c < CC; ++c) {
            float e = expf(__fsub_rn(row[c], mx));
            float sc = __fdiv_rn(e, s);
            if (sc > 0.01f) {
                unsigned int bits = __float_as_uint(sc);
                unsigned int bin = (bits - BASEBITS) >> CSHIFT;
                if (bin >= CBINS) bin = CBINS - 1;
                atomicAdd(&h[(c - 1) * (CBINS / 2) + (bin >> 1)],
                          (bin & 1) ? 65536u : 1u);
            }
        }
    }
    __syncthreads();
    unsigned int* dst = histg + (size_t)blockIdx.x * HWORDS;
    for (int i = tid; i < HWORDS; i += 256) dst[i] = h[i];
}

// ---------------- pass 2: per-(b,c) sum packed partials, find rank-100 bit cut ----------------
__global__ __launch_bounds__(64) void cut_kernel(const unsigned int* __restrict__ histg,
                                                 unsigned int* __restrict__ cuts) {
    int bc = blockIdx.x;              // b*80 + c
    int b = bc / CM1, c = bc % CM1;
    __shared__ unsigned int sh[CBINS];
    int t = threadIdx.x;
    if (t < CBINS / 2) {
        // per-image sums <= 24564 fit in 16 bits: packed u32 adds never carry
        unsigned int sum = 0;
        for (int jj = 0; jj < NTILES; ++jj)
            sum += histg[(size_t)(b * NTILES + jj) * HWORDS + c * (CBINS / 2) + t];
        sh[2 * t]     = sum & 0xFFFFu;
        sh[2 * t + 1] = sum >> 16;
    }
    __syncthreads();
    if (t == 0) {
        unsigned int total = 0;
        for (int i = 0; i < CBINS; ++i) total += sh[i];
        int Kt = (int)(total < KTOP ? total : KTOP);
        unsigned int cutv = 0xFFFFFFFFu;
        if (Kt > 0) {
            unsigned int cum = 0; int bb2 = 0;
            for (int i = CBINS - 1; i >= 0; --i) {
                cum += sh[i];
                if (cum >= (unsigned)Kt) { bb2 = i; break; }
            }
            unsigned int cutbin = (cum <= CAP2) ? (unsigned)bb2 : (unsigned)(bb2 + 1);
            cutv = BASEBITS + (cutbin << CSHIFT);
        }
        cuts[bc] = cutv;
    }
}

// ---------------- pass 3: coalesced re-read, identical softmax, collect candidates >= cut ----------------
__global__ __launch_bounds__(256) void collect_kernel(const float* __restrict__ conf,
                                                      const unsigned int* __restrict__ cuts,
                                                      ull* __restrict__ cand,
                                                      unsigned int* __restrict__ ccnt) {
    __shared__ __align__(16) float tile[TILE * CC];
    __shared__ unsigned int lcut[CM1];
    int tid = threadIdx.x;
    int b = blockIdx.x / NTILES, j = blockIdx.x % NTILES;
    if (tid < CM1) lcut[tid] = cuts[b * CM1 + tid];

    int n0 = j * TILE;
    int cnt = NN - n0; if (cnt > TILE) cnt = TILE;
    const float4* src4 = reinterpret_cast<const float4*>(conf + ((size_t)b * NN + n0) * CC);
    float4* tile4 = reinterpret_cast<float4*>(tile);
    int tot4 = (cnt * CC) >> 2;
    for (int i = tid; i < tot4; i += 256) tile4[i] = src4[i];
    __syncthreads();

    if (tid < cnt) {
        const float* row = tile + tid * CC;
        float mx = row[0];
        for (int c = 1; c < CC; ++c) mx = fmaxf(mx, row[c]);
        float s = 0.f;
        for (int c = 0; c < CC; ++c) s = __fadd_rn(s, expf(__fsub_rn(row[c], mx)));
        unsigned int n = (unsigned int)(n0 + tid);
        for (int c = 1; c < CC; ++c) {
            float e = expf(__fsub_rn(row[c], mx));
            float sc = __fdiv_rn(e, s);
            if (sc > 0.01f) {
                unsigned int bits = __float_as_uint(sc);
                if (bits >= lcut[c - 1]) {
                    int bc = b * CM1 + (c - 1);
                    unsigned int p = atomicAdd(ccnt + bc, 1u);
                    if (p < CAP2)
                        cand[(size_t)bc * CAP2 + p] =
                            (((ull)(~bits)) << 32) | n;
                }
            }
        }
    }
}

// ---------------- pass 4: per-(b,c) sort candidates + fused box decode + greedy NMS ----------------
__global__ __launch_bounds__(256) void nms_kernel(const ull* __restrict__ cand,
                                                  const unsigned int* __restrict__ ccnt,
                                                  const float* __restrict__ loc,
                                                  const float* __restrict__ priors,
                                                  float* __restrict__ nms_scores,
                                                  float* __restrict__ nms_boxes) {
    int bc = blockIdx.x;
    int bimg = bc / CM1;
    __shared__ ull arr[CAP2];                 // 16 KB
    __shared__ float bx[KTOP][4];
    __shared__ float sv[KTOP];
    __shared__ ull mlo[KTOP], mhi[KTOP];
    __shared__ ull keeplo, keephi;

    int tid = threadIdx.x;
    int cc = (int)ccnt[bc]; if (cc > CAP2) cc = CAP2;
    int S = 1; while (S < cc) S <<= 1; if (S < 2) S = 2;
    const ull* crow = cand + (size_t)bc * CAP2;
    for (int i = tid; i < S; i += 256) arr[i] = (i < cc) ? crow[i] : ~0ull;
    __syncthreads();

    for (int k = 2; k <= S; k <<= 1) {
        for (int jj = k >> 1; jj > 0; jj >>= 1) {
            for (int i = tid; i < S; i += 256) {
                int ixj = i ^ jj;
                if (ixj > i) {
                    ull a = arr[i], b2 = arr[ixj];
                    bool up = ((i & k) == 0);
                    if ((a > b2) == up) { arr[i] = b2; arr[ixj] = a; }
                }
            }
            __syncthreads();
        }
    }

    if (tid < KTOP) {
        float val = 0.f; unsigned int n = 0;
        if (tid < cc) {
            ull kk = arr[tid];
            val = __uint_as_float(~(unsigned int)(kk >> 32));
            n = (unsigned int)(kk & 0xFFFFFFFFu);
        }
        sv[tid] = val;
        float4 l = reinterpret_cast<const float4*>(loc)[(size_t)bimg * NN + n];
        float4 p = reinterpret_cast<const float4*>(priors)[n];
        float cx = __fadd_rn(__fmul_rn(__fmul_rn(l.x, 0.1f), p.z), p.x);
        float cy = __fadd_rn(__fmul_rn(__fmul_rn(l.y, 0.1f), p.w), p.y);
        float w  = __fmul_rn(expf(__fmul_rn(l.z, 0.2f)), p.z);
        float h  = __fmul_rn(expf(__fmul_rn(l.w, 0.2f)), p.w);
        bx[tid][0] = __fsub_rn(cx, __fmul_rn(w, 0.5f));
        bx[tid][1] = __fsub_rn(cy, __fmul_rn(h, 0.5f));
        bx[tid][2] = __fadd_rn(cx, __fmul_rn(w, 0.5f));
        bx[tid][3] = __fadd_rn(cy, __fmul_rn(h, 0.5f));
    }
    __syncthreads();

    if (tid < KTOP) {
        float x1 = bx[tid][0], y1 = bx[tid][1], x2 = bx[tid][2], y2 = bx[tid][3];
        float ai = __fmul_rn(fmaxf(__fsub_rn(x2, x1), 0.f), fmaxf(__fsub_rn(y2, y1), 0.f));
        ull lo = 0, hi = 0;
        for (int jj = 0; jj < KTOP; ++jj) {
            float jx1 = bx[jj][0], jy1 = bx[jj][1], jx2 = bx[jj][2], jy2 = bx[jj][3];
            float iw = fmaxf(__fsub_rn(fminf(x2, jx2), fmaxf(x1, jx1)), 0.f);
            float ih = fmaxf(__fsub_rn(fminf(y2, jy2), fmaxf(y1, jy1)), 0.f);
            float inter = __fmul_rn(iw, ih);
            float aj = __fmul_rn(fmaxf(__fsub_rn(jx2, jx1), 0.f), fmaxf(__fsub_rn(jy2, jy1), 0.f));
            float denom = __fadd_rn(__fsub_rn(__fadd_rn(ai, aj), inter), 1e-8f);
            float iou = __fdiv_rn(inter, denom);
            if (iou > 0.45f) { if (jj < 64) lo |= (1ull << jj); else hi |= (1ull << (jj - 64)); }
        }
        mlo[tid] = lo; mhi[tid] = hi;
    }
    __syncthreads();

    if (tid == 0) {
        ull klo = 0, khi = 0;
        for (int i = 0; i < KTOP; ++i) {
            ull sup = (mlo[i] & klo) | (mhi[i] & khi);
            bool kp = (sv[i] > 0.f) && (sup == 0ull);
            if (kp) { if (i < 64) klo |= (1ull << i); else khi |= (1ull << (i - 64)); }
        }
        keeplo = klo; keephi = khi;
    }
    __syncthreads();

    if (tid < KTOP) {
        bool kp = (tid < 64) ? ((keeplo >> tid) & 1ull) : ((keephi >> (tid - 64)) & 1ull);
        size_t obase = (size_t)bc * KTOP + tid;
        nms_scores[obase] = kp ? sv[tid] : 0.f;
        float4 o; o.x = bx[tid][0]; o.y = bx[tid][1]; o.z = bx[tid][2]; o.w = bx[tid][3];
        reinterpret_cast<float4*>(nms_boxes)[obase] = o;
    }
}

// ---------------- per-image final top-100 over 8000 candidates ----------------
__global__ __launch_bounds__(256) void final_topk_kernel(const float* __restrict__ nms_scores,
                                                         const float* __restrict__ nms_boxes,
                                                         float* __restrict__ out) {
    int b = blockIdx.x;
    __shared__ ull arr[8192];   // 64 KB
    int tid = threadIdx.x;
    const int NCAND = CM1 * KTOP;              // 8000
    const float* srow = nms_scores + (size_t)b * NCAND;
    for (int i = tid; i < 8192; i += 256) {
        ull key;
        if (i < NCAND) {
            float s = srow[i];
            unsigned int bits = (s > 0.f) ? __float_as_uint(s) : 0u;
            key = (((ull)(~bits)) << 32) | (unsigned int)i;
        } else key = ~0ull;
        arr[i] = key;
    }
    __syncthreads();
    for (int k = 2; k <= 8192; k <<= 1) {
        for (int jj = k >> 1; jj > 0; jj >>= 1) {
            for (int i = tid; i < 8192; i += 256) {
                int ixj = i ^ jj;
                if (ixj > i) {
                    ull a = arr[i], b2 = arr[ixj];
                    bool up = ((i & k) == 0);
                    if ((a > b2) == up) { arr[i] = b2; arr[ixj] = a; }
                }
            }
            __syncthreads();
        }
    }
    if (tid < MAXDET) {
        ull kk = arr[tid];
        unsigned int hb = (unsigned int)(kk >> 32);
        unsigned int idx = (unsigned int)(kk & 0xFFFFFFFFu);
        float val = __uint_as_float(~hb);
        float4 b4 = reinterpret_cast<const float4*>(nms_boxes)[(size_t)b * NCAND + idx];
        reinterpret_cast<float4*>(out)[(size_t)b * MAXDET + tid] = b4;
        out[BB * MAXDET * 4 + b * MAXDET + tid] = val;
        out[BB * MAXDET * 5 + b * MAXDET + tid] = (float)(idx / KTOP + 1);
    }
}

extern "C" void kernel_launch(void* const* d_in, const int* in_sizes, int n_in,
                              void* d_out, int out_size, void* d_ws, size_t ws_size,
                              hipStream_t stream) {
    const float* loc    = (const float*)d_in[0];
    const float* conf   = (const float*)d_in[1];
    const float* priors = (const float*)d_in[2];
    float* out = (float*)d_out;

    // workspace layout (16B-aligned chunks)
    char* ws = (char*)d_ws;
    float* nms_scores = (float*)ws;                                        // 32*8000           = 1.02 MB
    float* nms_boxes  = nms_scores + (size_t)BB * CM1 * KTOP;              // 32*8000*4         = 4.1 MB
    ull*   cand       = (ull*)(nms_boxes + (size_t)BB * CM1 * KTOP * 4);   // 2560*2048*8       = 41.9 MB
    unsigned int* histg = (unsigned int*)(cand + (size_t)BB * CM1 * CAP2); // 6144*1120*4       = 27.5 MB
    unsigned int* cuts  = histg + (size_t)BB * NTILES * HWORDS;            // 2560
    unsigned int* ccnt  = cuts + (size_t)BB * CM1;                         // 2560

    hipMemsetAsync(ccnt, 0, (size_t)BB * CM1 * sizeof(unsigned int), stream);

    softmax_hist_kernel<<<BB * NTILES, 256, 0, stream>>>(conf, histg);
    cut_kernel<<<BB * CM1, 64, 0, stream>>>(histg, cuts);
    collect_kernel<<<BB * NTILES, 256, 0, stream>>>(conf, cuts, cand, ccnt);
    nms_kernel<<<BB * CM1, 256, 0, stream>>>(cand, ccnt, loc, priors, nms_scores, nms_boxes);
    final_topk_kernel<<<BB, 256, 0, stream>>>(nms_scores, nms_boxes, out);
}